// Round 3
// 178.318 us; speedup vs baseline: 1.0057x; 1.0057x over previous
//
#include <hip/hip_runtime.h>
#include <math.h>

// ---------------------------------------------------------------------------
// Host-side: build stiffness matrix C = inv(Ci) in double precision (faithful
// to np.linalg.inv of the block-diagonal compliance matrix).
// ---------------------------------------------------------------------------
struct CParams {
    float b[3][3];  // inverse of the upper-left 3x3 compliance block
    float s;        // shear stiffness diagonal = Ep / (2*(1+vp)) = 0.075
};

static CParams make_C() {
    const double vp = 0.4, Ep = 0.21;
    double A[3][3] = {
        {1.0 / Ep, -vp / Ep, -vp / Ep},
        {-vp / Ep, 1.0 / Ep, -vp / Ep},
        {-vp,      -vp,      1.0 / Ep},   // note: -vp, NOT -vp/Ep (faithful)
    };
    double inv[3][3] = {{1, 0, 0}, {0, 1, 0}, {0, 0, 1}};
    for (int col = 0; col < 3; ++col) {
        int piv = col;
        for (int r = col + 1; r < 3; ++r)
            if (fabs(A[r][col]) > fabs(A[piv][col])) piv = r;
        if (piv != col) {
            for (int c = 0; c < 3; ++c) {
                double t = A[col][c]; A[col][c] = A[piv][c]; A[piv][c] = t;
                t = inv[col][c]; inv[col][c] = inv[piv][c]; inv[piv][c] = t;
            }
        }
        double d = A[col][col];
        for (int c = 0; c < 3; ++c) { A[col][c] /= d; inv[col][c] /= d; }
        for (int r = 0; r < 3; ++r) {
            if (r == col) continue;
            double f = A[r][col];
            for (int c = 0; c < 3; ++c) {
                A[r][c] -= f * A[col][c];
                inv[r][c] -= f * inv[col][c];
            }
        }
    }
    CParams p;
    for (int i = 0; i < 3; ++i)
        for (int j = 0; j < 3; ++j)
            p.b[i][j] = (float)inv[i][j];
    p.s = (float)(Ep / (2.0 * (1.0 + vp)));
    return p;
}

static const CParams g_C = make_C();

#define MAXB 2048   // partial-sum slots in workspace
#define TPB  256    // threads per block (4 waves)

// ---------------------------------------------------------------------------
// Main reduction — barrier-free grid-stride, 4 points per thread.
//
// Layout insight: grad_* is (N,3) row-major. If thread t owns points
// 4t..4t+3, the 12 floats it needs from each array are exactly float4
// indices [3t, 3t+1, 3t+2] — three dwordx4 loads whose union over a wave
// is a fully-dense contiguous 3 KB region (every cache line 100% used).
// No transpose, no LDS staging, no __syncthreads in the hot loop — so no
// compiler-forced s_waitcnt vmcnt(0) barrier drains; loads pipeline freely
// across grid-stride iterations. 10 loads (160 B) in flight per thread,
// ~32 waves/CU (no LDS, low VGPR) → latency-hiding by TLP+ILP.
// ---------------------------------------------------------------------------
__device__ __forceinline__ void accum_point(
    float u0, float u1, float u2,
    float v0, float v1, float v2,
    float w0, float w1, float w2,
    float sd, const CParams& C, float& sumq2, float& cnt)
{
    float e0 = u0, e1 = v1, e2 = w2;
    float e3 = 0.5f * (u1 + v0);
    float e4 = 0.5f * (u2 + w0);
    float e5 = 0.5f * (w1 + v2);

    float q = e0 * (C.b[0][0] * e0 + C.b[0][1] * e1 + C.b[0][2] * e2)
            + e1 * (C.b[1][0] * e0 + C.b[1][1] * e1 + C.b[1][2] * e2)
            + e2 * (C.b[2][0] * e0 + C.b[2][1] * e1 + C.b[2][2] * e2)
            + C.s * (e3 * e3 + e4 * e4 + e5 * e5);

    bool m = sd < 1e-8f;
    float qm = m ? q : 0.0f;
    sumq2 += qm * qm;
    cnt   += m ? 1.0f : 0.0f;
}

__global__ __launch_bounds__(TPB) void biomech_reduce(
    const float* __restrict__ gu, const float* __restrict__ gv,
    const float* __restrict__ gw, const float* __restrict__ gs,
    float* __restrict__ ws, int n, CParams C)
{
    const int tid    = blockIdx.x * TPB + threadIdx.x;
    const int stride = gridDim.x * TPB;
    const int nvec   = n >> 2;          // groups of 4 points

    const float4* u4 = (const float4*)gu;
    const float4* v4 = (const float4*)gv;
    const float4* w4 = (const float4*)gw;
    const float4* s4 = (const float4*)gs;

    float sumq2 = 0.0f, cnt = 0.0f;

    for (int i = tid; i < nvec; i += stride) {
        const int b = 3 * i;
        // 10 independent 16B loads — issued together, consumed after.
        float4 a0 = u4[b], a1 = u4[b + 1], a2 = u4[b + 2];
        float4 b0 = v4[b], b1 = v4[b + 1], b2 = v4[b + 2];
        float4 c0 = w4[b], c1 = w4[b + 1], c2 = w4[b + 2];
        float4 sd = s4[i];

        // point 0: floats 0..2, point 1: 3..5, point 2: 6..8, point 3: 9..11
        accum_point(a0.x, a0.y, a0.z,  b0.x, b0.y, b0.z,  c0.x, c0.y, c0.z,
                    sd.x, C, sumq2, cnt);
        accum_point(a0.w, a1.x, a1.y,  b0.w, b1.x, b1.y,  c0.w, c1.x, c1.y,
                    sd.y, C, sumq2, cnt);
        accum_point(a1.z, a1.w, a2.x,  b1.z, b1.w, b2.x,  c1.z, c1.w, c2.x,
                    sd.z, C, sumq2, cnt);
        accum_point(a2.y, a2.z, a2.w,  b2.y, b2.z, b2.w,  c2.y, c2.z, c2.w,
                    sd.w, C, sumq2, cnt);
    }

    // Tail (n not divisible by 4) — global thread 0 only.
    if (blockIdx.x == 0 && threadIdx.x == 0) {
        for (int i = nvec * 4; i < n; ++i) {
            accum_point(gu[3 * i], gu[3 * i + 1], gu[3 * i + 2],
                        gv[3 * i], gv[3 * i + 1], gv[3 * i + 2],
                        gw[3 * i], gw[3 * i + 1], gw[3 * i + 2],
                        gs[i], C, sumq2, cnt);
        }
    }

    // Wave (64-lane) shuffle reduction
#pragma unroll
    for (int off = 32; off > 0; off >>= 1) {
        sumq2 += __shfl_down(sumq2, off);
        cnt   += __shfl_down(cnt, off);
    }

    __shared__ float ssum[TPB / 64], scnt[TPB / 64];
    const int wave = threadIdx.x >> 6;
    const int lane = threadIdx.x & 63;
    if (lane == 0) { ssum[wave] = sumq2; scnt[wave] = cnt; }
    __syncthreads();
    if (threadIdx.x == 0) {
        float s2 = 0.0f, c2 = 0.0f;
#pragma unroll
        for (int i = 0; i < TPB / 64; ++i) { s2 += ssum[i]; c2 += scnt[i]; }
        ws[blockIdx.x]        = s2;   // contention-free per-block store
        ws[MAXB + blockIdx.x] = c2;
    }
}

// ---------------------------------------------------------------------------
// Finalize: single block reduces nb partial pairs, writes sqrt(sum)/count.
// ---------------------------------------------------------------------------
__global__ __launch_bounds__(256) void biomech_finalize(
    const float* __restrict__ ws, float* __restrict__ out, int nb)
{
    float s = 0.0f, c = 0.0f;
    for (int i = threadIdx.x; i < nb; i += 256) {
        s += ws[i];
        c += ws[MAXB + i];
    }
#pragma unroll
    for (int off = 32; off > 0; off >>= 1) {
        s += __shfl_down(s, off);
        c += __shfl_down(c, off);
    }
    __shared__ float ssum[4], scnt[4];
    const int wave = threadIdx.x >> 6;
    const int lane = threadIdx.x & 63;
    if (lane == 0) { ssum[wave] = s; scnt[wave] = c; }
    __syncthreads();
    if (threadIdx.x == 0) {
        float s2 = ssum[0] + ssum[1] + ssum[2] + ssum[3];
        float c2 = scnt[0] + scnt[1] + scnt[2] + scnt[3];
        out[0] = sqrtf(s2) / c2;
    }
}

extern "C" void kernel_launch(void* const* d_in, const int* in_sizes, int n_in,
                              void* d_out, int out_size, void* d_ws, size_t ws_size,
                              hipStream_t stream) {
    const float* gu = (const float*)d_in[0];
    const float* gv = (const float*)d_in[1];
    const float* gw = (const float*)d_in[2];
    const float* gs = (const float*)d_in[3];
    float* ws = (float*)d_ws;
    float* out = (float*)d_out;

    const int n = in_sizes[3];      // number of points (gt_sdf length)
    const int nvec = n >> 2;

    int grid = (nvec + TPB - 1) / TPB;
    if (grid > 2048) grid = 2048;   // 8 blocks/CU, grid-stride the rest
    if (grid > MAXB) grid = MAXB;
    while (grid > 1 && (size_t)(MAXB + grid) * sizeof(float) > ws_size) grid >>= 1;
    if (grid < 1) grid = 1;

    biomech_reduce<<<grid, TPB, 0, stream>>>(gu, gv, gw, gs, ws, n, g_C);
    biomech_finalize<<<1, 256, 0, stream>>>(ws, out, grid);
}

// Round 4
// 177.075 us; speedup vs baseline: 1.0128x; 1.0070x over previous
//
#include <hip/hip_runtime.h>
#include <math.h>

// ---------------------------------------------------------------------------
// Host-side: build stiffness matrix C = inv(Ci) in double precision (faithful
// to np.linalg.inv of the block-diagonal compliance matrix).
// ---------------------------------------------------------------------------
struct CParams {
    float b[3][3];  // inverse of the upper-left 3x3 compliance block
    float s;        // shear stiffness diagonal = Ep / (2*(1+vp)) = 0.075
};

static CParams make_C() {
    const double vp = 0.4, Ep = 0.21;
    double A[3][3] = {
        {1.0 / Ep, -vp / Ep, -vp / Ep},
        {-vp / Ep, 1.0 / Ep, -vp / Ep},
        {-vp,      -vp,      1.0 / Ep},   // note: -vp, NOT -vp/Ep (faithful)
    };
    double inv[3][3] = {{1, 0, 0}, {0, 1, 0}, {0, 0, 1}};
    for (int col = 0; col < 3; ++col) {
        int piv = col;
        for (int r = col + 1; r < 3; ++r)
            if (fabs(A[r][col]) > fabs(A[piv][col])) piv = r;
        if (piv != col) {
            for (int c = 0; c < 3; ++c) {
                double t = A[col][c]; A[col][c] = A[piv][c]; A[piv][c] = t;
                t = inv[col][c]; inv[col][c] = inv[piv][c]; inv[piv][c] = t;
            }
        }
        double d = A[col][col];
        for (int c = 0; c < 3; ++c) { A[col][c] /= d; inv[col][c] /= d; }
        for (int r = 0; r < 3; ++r) {
            if (r == col) continue;
            double f = A[r][col];
            for (int c = 0; c < 3; ++c) {
                A[r][c] -= f * A[col][c];
                inv[r][c] -= f * inv[col][c];
            }
        }
    }
    CParams p;
    for (int i = 0; i < 3; ++i)
        for (int j = 0; j < 3; ++j)
            p.b[i][j] = (float)inv[i][j];
    p.s = (float)(Ep / (2.0 * (1.0 + vp)));
    return p;
}

static const CParams g_C = make_C();

#define MAXB 2048   // partial-sum slots in workspace
#define TPB  256    // threads per block (4 waves)

// ---------------------------------------------------------------------------
// Nontemporal 16B load. float4 is a struct (not a native vector), so go
// through ext_vector_type for __builtin_nontemporal_load. Emits
// global_load_dwordx4 with the nt cache-bypass bit on gfx950.
// ---------------------------------------------------------------------------
typedef float vfloat4 __attribute__((ext_vector_type(4)));

__device__ __forceinline__ float4 ntload4(const float* p) {
    vfloat4 v = __builtin_nontemporal_load((const vfloat4*)p);
    return make_float4(v.x, v.y, v.z, v.w);
}

// ---------------------------------------------------------------------------
// Main reduction — barrier-free grid-stride, 4 points per thread,
// NONTEMPORAL loads (single variable changed vs round 3).
//
// Round-0 (LDS/coalesced/16 waves) and round-3 (strided/barrier-free/32
// waves) both measured 64 us = 2.6 TB/s delivered, HBM at 1.3 TB/s,
// FETCH_SIZE = exactly half the 168 MB footprint. Structure-invariant =>
// the limiter is the cache path for this mostly-L3-resident read mix.
// nt loads bypass cache retention -> pure HBM streaming (m13: 6.3 TB/s).
// ---------------------------------------------------------------------------
__device__ __forceinline__ void accum_point(
    float u0, float u1, float u2,
    float v0, float v1, float v2,
    float w0, float w1, float w2,
    float sd, const CParams& C, float& sumq2, float& cnt)
{
    float e0 = u0, e1 = v1, e2 = w2;
    float e3 = 0.5f * (u1 + v0);
    float e4 = 0.5f * (u2 + w0);
    float e5 = 0.5f * (w1 + v2);

    float q = e0 * (C.b[0][0] * e0 + C.b[0][1] * e1 + C.b[0][2] * e2)
            + e1 * (C.b[1][0] * e0 + C.b[1][1] * e1 + C.b[1][2] * e2)
            + e2 * (C.b[2][0] * e0 + C.b[2][1] * e1 + C.b[2][2] * e2)
            + C.s * (e3 * e3 + e4 * e4 + e5 * e5);

    bool m = sd < 1e-8f;
    float qm = m ? q : 0.0f;
    sumq2 += qm * qm;
    cnt   += m ? 1.0f : 0.0f;
}

__global__ __launch_bounds__(TPB) void biomech_reduce(
    const float* __restrict__ gu, const float* __restrict__ gv,
    const float* __restrict__ gw, const float* __restrict__ gs,
    float* __restrict__ ws, int n, CParams C)
{
    const int tid    = blockIdx.x * TPB + threadIdx.x;
    const int stride = gridDim.x * TPB;
    const int nvec   = n >> 2;          // groups of 4 points

    float sumq2 = 0.0f, cnt = 0.0f;

    for (int i = tid; i < nvec; i += stride) {
        const float* pu = gu + 12 * i;
        const float* pv = gv + 12 * i;
        const float* pw = gw + 12 * i;
        // 10 independent 16B nt loads — issued together, consumed after.
        float4 a0 = ntload4(pu), a1 = ntload4(pu + 4), a2 = ntload4(pu + 8);
        float4 b0 = ntload4(pv), b1 = ntload4(pv + 4), b2 = ntload4(pv + 8);
        float4 c0 = ntload4(pw), c1 = ntload4(pw + 4), c2 = ntload4(pw + 8);
        float4 sd = ntload4(gs + 4 * i);

        // point 0: floats 0..2, point 1: 3..5, point 2: 6..8, point 3: 9..11
        accum_point(a0.x, a0.y, a0.z,  b0.x, b0.y, b0.z,  c0.x, c0.y, c0.z,
                    sd.x, C, sumq2, cnt);
        accum_point(a0.w, a1.x, a1.y,  b0.w, b1.x, b1.y,  c0.w, c1.x, c1.y,
                    sd.y, C, sumq2, cnt);
        accum_point(a1.z, a1.w, a2.x,  b1.z, b1.w, b2.x,  c1.z, c1.w, c2.x,
                    sd.z, C, sumq2, cnt);
        accum_point(a2.y, a2.z, a2.w,  b2.y, b2.z, b2.w,  c2.y, c2.z, c2.w,
                    sd.w, C, sumq2, cnt);
    }

    // Tail (n not divisible by 4) — global thread 0 only.
    if (blockIdx.x == 0 && threadIdx.x == 0) {
        for (int i = nvec * 4; i < n; ++i) {
            accum_point(gu[3 * i], gu[3 * i + 1], gu[3 * i + 2],
                        gv[3 * i], gv[3 * i + 1], gv[3 * i + 2],
                        gw[3 * i], gw[3 * i + 1], gw[3 * i + 2],
                        gs[i], C, sumq2, cnt);
        }
    }

    // Wave (64-lane) shuffle reduction
#pragma unroll
    for (int off = 32; off > 0; off >>= 1) {
        sumq2 += __shfl_down(sumq2, off);
        cnt   += __shfl_down(cnt, off);
    }

    __shared__ float ssum[TPB / 64], scnt[TPB / 64];
    const int wave = threadIdx.x >> 6;
    const int lane = threadIdx.x & 63;
    if (lane == 0) { ssum[wave] = sumq2; scnt[wave] = cnt; }
    __syncthreads();
    if (threadIdx.x == 0) {
        float s2 = 0.0f, c2 = 0.0f;
#pragma unroll
        for (int i = 0; i < TPB / 64; ++i) { s2 += ssum[i]; c2 += scnt[i]; }
        ws[blockIdx.x]        = s2;   // contention-free per-block store
        ws[MAXB + blockIdx.x] = c2;
    }
}

// ---------------------------------------------------------------------------
// Finalize: single block reduces nb partial pairs, writes sqrt(sum)/count.
// ---------------------------------------------------------------------------
__global__ __launch_bounds__(256) void biomech_finalize(
    const float* __restrict__ ws, float* __restrict__ out, int nb)
{
    float s = 0.0f, c = 0.0f;
    for (int i = threadIdx.x; i < nb; i += 256) {
        s += ws[i];
        c += ws[MAXB + i];
    }
#pragma unroll
    for (int off = 32; off > 0; off >>= 1) {
        s += __shfl_down(s, off);
        c += __shfl_down(c, off);
    }
    __shared__ float ssum[4], scnt[4];
    const int wave = threadIdx.x >> 6;
    const int lane = threadIdx.x & 63;
    if (lane == 0) { ssum[wave] = s; scnt[wave] = c; }
    __syncthreads();
    if (threadIdx.x == 0) {
        float s2 = ssum[0] + ssum[1] + ssum[2] + ssum[3];
        float c2 = scnt[0] + scnt[1] + scnt[2] + scnt[3];
        out[0] = sqrtf(s2) / c2;
    }
}

extern "C" void kernel_launch(void* const* d_in, const int* in_sizes, int n_in,
                              void* d_out, int out_size, void* d_ws, size_t ws_size,
                              hipStream_t stream) {
    const float* gu = (const float*)d_in[0];
    const float* gv = (const float*)d_in[1];
    const float* gw = (const float*)d_in[2];
    const float* gs = (const float*)d_in[3];
    float* ws = (float*)d_ws;
    float* out = (float*)d_out;

    const int n = in_sizes[3];      // number of points (gt_sdf length)
    const int nvec = n >> 2;

    int grid = (nvec + TPB - 1) / TPB;
    if (grid > 2048) grid = 2048;   // 8 blocks/CU, grid-stride the rest
    if (grid > MAXB) grid = MAXB;
    while (grid > 1 && (size_t)(MAXB + grid) * sizeof(float) > ws_size) grid >>= 1;
    if (grid < 1) grid = 1;

    biomech_reduce<<<grid, TPB, 0, stream>>>(gu, gv, gw, gs, ws, n, g_C);
    biomech_finalize<<<1, 256, 0, stream>>>(ws, out, grid);
}

// Round 6
// 160.894 us; speedup vs baseline: 1.1146x; 1.1006x over previous
//
#include <hip/hip_runtime.h>
#include <math.h>

// ---------------------------------------------------------------------------
// Host-side: build stiffness matrix C = inv(Ci) in double precision (faithful
// to np.linalg.inv of the block-diagonal compliance matrix).
// ---------------------------------------------------------------------------
struct CParams {
    float b[3][3];  // inverse of the upper-left 3x3 compliance block
    float s;        // shear stiffness diagonal = Ep / (2*(1+vp)) = 0.075
};

static CParams make_C() {
    const double vp = 0.4, Ep = 0.21;
    double A[3][3] = {
        {1.0 / Ep, -vp / Ep, -vp / Ep},
        {-vp / Ep, 1.0 / Ep, -vp / Ep},
        {-vp,      -vp,      1.0 / Ep},   // note: -vp, NOT -vp/Ep (faithful)
    };
    double inv[3][3] = {{1, 0, 0}, {0, 1, 0}, {0, 0, 1}};
    for (int col = 0; col < 3; ++col) {
        int piv = col;
        for (int r = col + 1; r < 3; ++r)
            if (fabs(A[r][col]) > fabs(A[piv][col])) piv = r;
        if (piv != col) {
            for (int c = 0; c < 3; ++c) {
                double t = A[col][c]; A[col][c] = A[piv][c]; A[piv][c] = t;
                t = inv[col][c]; inv[col][c] = inv[piv][c]; inv[piv][c] = t;
            }
        }
        double d = A[col][col];
        for (int c = 0; c < 3; ++c) { A[col][c] /= d; inv[col][c] /= d; }
        for (int r = 0; r < 3; ++r) {
            if (r == col) continue;
            double f = A[r][col];
            for (int c = 0; c < 3; ++c) {
                A[r][c] -= f * A[col][c];
                inv[r][c] -= f * inv[col][c];
            }
        }
    }
    CParams p;
    for (int i = 0; i < 3; ++i)
        for (int j = 0; j < 3; ++j)
            p.b[i][j] = (float)inv[i][j];
    p.s = (float)(Ep / (2.0 * (1.0 + vp)));
    return p;
}

static const CParams g_C = make_C();

#define MAXB  2048        // partial-sum slots in workspace
#define TPB   256         // threads per block (4 waves)
#define WPB   (TPB / 64)  // waves per block
#define CHUNK 256         // points per wave-chunk
#define TILEP (WPB * CHUNK) // 1024 points per block-tile
#define F4PW  192         // float4s per array per wave-chunk (256*3/4)

// Compiler-level memory fence, zero instructions. Needed because per-thread
// alias analysis can PROVE e.g. lu[3*lane+1] disjoint from this thread's own
// stores {lane,64+lane,128+lane} (2l=63/127 unsolvable) and hoist the
// ds_read above the ds_writes — a cross-lane RAW race (round-5 failure,
// absmax 1.3e-2). HW side is safe: the LDS pipe processes one wave's DS ops
// in order, so a compiler fence alone restores correctness, no s_barrier.
#define WAVE_FENCE() asm volatile("" ::: "memory")

// ---------------------------------------------------------------------------
// Nontemporal 16B load (cache-bypass nt bit; round 4 proved this lifts the
// cache-retention limit: 64.6 -> 45.5 us).
// ---------------------------------------------------------------------------
typedef float vfloat4 __attribute__((ext_vector_type(4)));

__device__ __forceinline__ float4 ntload4(const float* p) {
    vfloat4 v = __builtin_nontemporal_load((const vfloat4*)p);
    return make_float4(v.x, v.y, v.z, v.w);
}

// ---------------------------------------------------------------------------
// Round-4 post-mortem: 48B-lane-stride dwordx4 loads touch the same 128B
// lines 3x (72 line-requests per 24 unique lines per wave-region). Delivered
// 2.75 TB/s x 3 = 8.25 TB/s request-path bandwidth = the fabric ceiling ->
// we saturate the request path with duplicate line lookups.
//
// This version: DENSE per-instruction loads (16B lane stride, 1x requests)
// + wave-private LDS regather, barrier-free but COMPILER-FENCED:
//  - per 256-point wave-chunk: 3 dense nt dwordx4 per gradient array
//    (lane l -> float4 base+{l,64+l,128+l}) + 1 dense sdf float4.
//  - float4 stores into the wave's LDS slice; WAVE_FENCE(); float4 reads
//    back at index {3l,3l+1,3l+2} (floats 12l..12l+11 = points 4l..4l+3);
//    WAVE_FENCE() at loop bottom covers the WAR vs next iter's stores.
//  - lane's own dense sdf float4 = exactly the mask for its 4 points.
// 36 KB LDS/block -> 4 blocks/CU (16 waves/CU); BW-bound steady state needs
// ~10 B/cyc/CU so TLP covers all latency.
// ---------------------------------------------------------------------------
__device__ __forceinline__ void accum_point(
    float u0, float u1, float u2,
    float v0, float v1, float v2,
    float w0, float w1, float w2,
    float sd, const CParams& C, float& sumq2, float& cnt)
{
    float e0 = u0, e1 = v1, e2 = w2;
    float e3 = 0.5f * (u1 + v0);
    float e4 = 0.5f * (u2 + w0);
    float e5 = 0.5f * (w1 + v2);

    float q = e0 * (C.b[0][0] * e0 + C.b[0][1] * e1 + C.b[0][2] * e2)
            + e1 * (C.b[1][0] * e0 + C.b[1][1] * e1 + C.b[1][2] * e2)
            + e2 * (C.b[2][0] * e0 + C.b[2][1] * e1 + C.b[2][2] * e2)
            + C.s * (e3 * e3 + e4 * e4 + e5 * e5);

    bool m = sd < 1e-8f;
    float qm = m ? q : 0.0f;
    sumq2 += qm * qm;
    cnt   += m ? 1.0f : 0.0f;
}

__global__ __launch_bounds__(TPB) void biomech_reduce(
    const float* __restrict__ gu, const float* __restrict__ gv,
    const float* __restrict__ gw, const float* __restrict__ gs,
    float* __restrict__ ws, int n, CParams C)
{
    __shared__ float4 buf[WPB][3][F4PW];

    const int wave = threadIdx.x >> 6;
    const int lane = threadIdx.x & 63;
    const int ntiles = n / TILEP;

    float4* lu = &buf[wave][0][0];
    float4* lv = &buf[wave][1][0];
    float4* lw = &buf[wave][2][0];

    float sumq2 = 0.0f, cnt = 0.0f;

    for (int t = blockIdx.x; t < ntiles; t += gridDim.x) {
        const int gb = t * (TILEP * 3 / 4) + wave * F4PW;  // float4 idx, grads
        const int sb = t * (TILEP / 4)     + wave * 64;    // float4 idx, sdf

        // dense nt loads: lane stride 16B, every 128B line requested once
        float4 A0 = ntload4(gu + 4 * (gb + lane));
        float4 A1 = ntload4(gu + 4 * (gb + 64 + lane));
        float4 A2 = ntload4(gu + 4 * (gb + 128 + lane));
        float4 B0 = ntload4(gv + 4 * (gb + lane));
        float4 B1 = ntload4(gv + 4 * (gb + 64 + lane));
        float4 B2 = ntload4(gv + 4 * (gb + 128 + lane));
        float4 C0 = ntload4(gw + 4 * (gb + lane));
        float4 C1 = ntload4(gw + 4 * (gb + 64 + lane));
        float4 C2 = ntload4(gw + 4 * (gb + 128 + lane));
        float4 SD = ntload4(gs + 4 * (sb + lane));

        // stage into this wave's private LDS slice (float4-typed both sides)
        lu[lane] = A0; lu[64 + lane] = A1; lu[128 + lane] = A2;
        lv[lane] = B0; lv[64 + lane] = B1; lv[128 + lane] = B2;
        lw[lane] = C0; lw[64 + lane] = C1; lw[128 + lane] = C2;

        WAVE_FENCE();   // RAW: no read may be hoisted above the stores

        // regather: floats 12l..12l+11 = this lane's points 4l..4l+3
        float4 a0 = lu[3 * lane], a1 = lu[3 * lane + 1], a2 = lu[3 * lane + 2];
        float4 b0 = lv[3 * lane], b1 = lv[3 * lane + 1], b2 = lv[3 * lane + 2];
        float4 c0 = lw[3 * lane], c1 = lw[3 * lane + 1], c2 = lw[3 * lane + 2];

        WAVE_FENCE();   // WAR: next iter's stores may not sink above reads

        accum_point(a0.x, a0.y, a0.z,  b0.x, b0.y, b0.z,  c0.x, c0.y, c0.z,
                    SD.x, C, sumq2, cnt);
        accum_point(a0.w, a1.x, a1.y,  b0.w, b1.x, b1.y,  c0.w, c1.x, c1.y,
                    SD.y, C, sumq2, cnt);
        accum_point(a1.z, a1.w, a2.x,  b1.z, b1.w, b2.x,  c1.z, c1.w, c2.x,
                    SD.z, C, sumq2, cnt);
        accum_point(a2.y, a2.z, a2.w,  b2.y, b2.z, b2.w,  c2.y, c2.z, c2.w,
                    SD.w, C, sumq2, cnt);
    }

    // Tail (n not divisible by TILEP) — global thread 0 only.
    if (blockIdx.x == 0 && threadIdx.x == 0) {
        for (int i = ntiles * TILEP; i < n; ++i) {
            accum_point(gu[3 * i], gu[3 * i + 1], gu[3 * i + 2],
                        gv[3 * i], gv[3 * i + 1], gv[3 * i + 2],
                        gw[3 * i], gw[3 * i + 1], gw[3 * i + 2],
                        gs[i], C, sumq2, cnt);
        }
    }

    // Wave (64-lane) shuffle reduction
#pragma unroll
    for (int off = 32; off > 0; off >>= 1) {
        sumq2 += __shfl_down(sumq2, off);
        cnt   += __shfl_down(cnt, off);
    }

    __shared__ float ssum[WPB], scnt[WPB];
    if (lane == 0) { ssum[wave] = sumq2; scnt[wave] = cnt; }
    __syncthreads();
    if (threadIdx.x == 0) {
        float s2 = 0.0f, c2 = 0.0f;
#pragma unroll
        for (int i = 0; i < WPB; ++i) { s2 += ssum[i]; c2 += scnt[i]; }
        ws[blockIdx.x]        = s2;   // contention-free per-block store
        ws[MAXB + blockIdx.x] = c2;
    }
}

// ---------------------------------------------------------------------------
// Finalize: single block reduces nb partial pairs, writes sqrt(sum)/count.
// ---------------------------------------------------------------------------
__global__ __launch_bounds__(256) void biomech_finalize(
    const float* __restrict__ ws, float* __restrict__ out, int nb)
{
    float s = 0.0f, c = 0.0f;
    for (int i = threadIdx.x; i < nb; i += 256) {
        s += ws[i];
        c += ws[MAXB + i];
    }
#pragma unroll
    for (int off = 32; off > 0; off >>= 1) {
        s += __shfl_down(s, off);
        c += __shfl_down(c, off);
    }
    __shared__ float ssum[4], scnt[4];
    const int wave = threadIdx.x >> 6;
    const int lane = threadIdx.x & 63;
    if (lane == 0) { ssum[wave] = s; scnt[wave] = c; }
    __syncthreads();
    if (threadIdx.x == 0) {
        float s2 = ssum[0] + ssum[1] + ssum[2] + ssum[3];
        float c2 = scnt[0] + scnt[1] + scnt[2] + scnt[3];
        out[0] = sqrtf(s2) / c2;
    }
}

extern "C" void kernel_launch(void* const* d_in, const int* in_sizes, int n_in,
                              void* d_out, int out_size, void* d_ws, size_t ws_size,
                              hipStream_t stream) {
    const float* gu = (const float*)d_in[0];
    const float* gv = (const float*)d_in[1];
    const float* gw = (const float*)d_in[2];
    const float* gs = (const float*)d_in[3];
    float* ws = (float*)d_ws;
    float* out = (float*)d_out;

    const int n = in_sizes[3];      // number of points (gt_sdf length)
    const int ntiles = n / TILEP;

    int grid = ntiles > 0 ? ntiles : 1;
    if (grid > 2048) grid = 2048;   // 4 blocks/CU (36 KB LDS) x 2 tiles each
    if (grid > MAXB) grid = MAXB;
    while (grid > 1 && (size_t)(MAXB + grid) * sizeof(float) > ws_size) grid >>= 1;
    if (grid < 1) grid = 1;

    biomech_reduce<<<grid, TPB, 0, stream>>>(gu, gv, gw, gs, ws, n, g_C);
    biomech_finalize<<<1, 256, 0, stream>>>(ws, out, grid);
}